// Round 5
// baseline (718.597 us; speedup 1.0000x reference)
//
#include <hip/hip_runtime.h>
#include <hip/hip_bf16.h>

// Problem constants
#define N_ROWS 16384   // 8*2048
#define DDIM   512
#define KCODES 8192
#define BETA   0.25f
#define DECAY  0.99f
#define ONE_MINUS_DECAY 0.01f
#define EMA_EPS 1e-5f

// Output layout (floats, concatenated in reference return order)
#define O_Z    0                 // z_out: 8388608
#define O_LOSS 8388608           // vq_loss: 1
#define O_CS   8388609           // new_ema_cluster_size: 8192
#define O_AVG  8396801           // new_ema_embed_avg: 4194304
#define O_CB   12591105          // new_codebook: 4194304

// Workspace layout (bytes), all 256-aligned; total ~25.5 MB
#define WS_CNT      0            // int[8192]            32 KB
#define WS_ESQ      32768        // float[8192]          32 KB
#define WS_FLAGCNT  65536        // int (+pad)           256 B
#define WS_FLAGLIST 65792        // int[2048]            8 KB
#define WS_KEYS     73984        // u64[16384]           128 KB
#define WS_SEC2     205056       // u32[16384]           64 KB
#define WS_LOSSP    270592       // float[64]            256 B
#define WS_IDXS     270848       // int[16384]           64 KB
#define WS_OFFS     336384       // int[8192]            32 KB
#define WS_CURS     369152       // int[8192]            32 KB
#define WS_ROWLIST  401920       // int[16384]           64 KB
#define WS_Z16      467456       // f16[16384*512]       16 MB
#define WS_CB16     17244672     // f16[8192*512]        8 MB   (end ~25.6 MB)

#define TAU  0.35f
#define RCAP 2048

typedef _Float16 half8  __attribute__((ext_vector_type(8)));
typedef float    floatx4 __attribute__((ext_vector_type(4)));

// monotone float<->u32 (ascending order preserved)
__device__ __forceinline__ unsigned enc_f(float d) {
    unsigned ub = __float_as_uint(d);
    return (ub & 0x80000000u) ? ~ub : (ub | 0x80000000u);
}
__device__ __forceinline__ float dec32(unsigned ub) {
    return __uint_as_float((ub & 0x80000000u) ? (ub ^ 0x80000000u) : ~ub);
}
__device__ __forceinline__ float dec_key(unsigned long long k) {
    return dec32((unsigned)(k >> 32));
}

__device__ __forceinline__ float4 pack8_f16(float4 a, float4 b) {
    auto p0 = __builtin_amdgcn_cvt_pkrtz(a.x, a.y);
    auto p1 = __builtin_amdgcn_cvt_pkrtz(a.z, a.w);
    auto p2 = __builtin_amdgcn_cvt_pkrtz(b.x, b.y);
    auto p3 = __builtin_amdgcn_cvt_pkrtz(b.z, b.w);
    float4 r;
    r.x = __builtin_bit_cast(float, p0);
    r.y = __builtin_bit_cast(float, p1);
    r.z = __builtin_bit_cast(float, p2);
    r.w = __builtin_bit_cast(float, p3);
    return r;
}

// global->LDS direct DMA, 16 B per lane. LDS dest = wave-uniform base + lane*16.
__device__ __forceinline__ void load_lds16(const void* g, void* l) {
    __builtin_amdgcn_global_load_lds(
        (const __attribute__((address_space(1))) unsigned int*)g,
        (__attribute__((address_space(3))) unsigned int*)l, 16, 0, 0);
}

// ---------------- cvtz: z fp32 -> f16, plus workspace init (replaces 4 memsets) --------
__global__ __launch_bounds__(256) void cvtz_kernel(const float* __restrict__ z,
                                                   _Float16* __restrict__ z16,
                                                   unsigned long long* __restrict__ keys,
                                                   unsigned* __restrict__ sec2,
                                                   float* __restrict__ lossp,
                                                   int* __restrict__ flagcnt) {
    size_t i = (size_t)blockIdx.x * 256 + threadIdx.x;   // 8 elems per thread
    const float4* p = (const float4*)z + 2 * i;
    ((float4*)z16)[i] = pack8_f16(p[0], p[1]);
    // init section: screen/merge/zout consumers all launch after cvtz in-stream
    if (i < N_ROWS) { keys[i] = ~0ULL; sec2[i] = 0xFFFFFFFFu; }
    if (i < 64) lossp[i] = 0.0f;
    if (i == 0) *flagcnt = 0;
}

// ---------------- cvtcb: cb fp32 -> f16 + e_sq + cnt zero ----------------
__global__ __launch_bounds__(64) void cvtcb_kernel(const float* __restrict__ cb,
                                                   _Float16* __restrict__ cb16,
                                                   float* __restrict__ e_sq,
                                                   int* __restrict__ cnt) {
    int k = blockIdx.x;
    int t = threadIdx.x;
    const float4* r = (const float4*)(cb + (size_t)k * DDIM);
    float4 a = r[2 * t], b = r[2 * t + 1];
    ((float4*)(cb16 + (size_t)k * DDIM))[t] = pack8_f16(a, b);
    float s = a.x*a.x + a.y*a.y + a.z*a.z + a.w*a.w
            + b.x*b.x + b.y*b.y + b.z*b.z + b.w*b.w;
    #pragma unroll
    for (int o = 32; o > 0; o >>= 1) s += __shfl_down(s, o);
    if (t == 0) { e_sq[k] = s; cnt[k] = 0; }
}

// ---------------- screen v3: f16 MFMA, 128x128 tile, 8 waves of 64x32 ----------------
// 512 thr = 8 waves (2m x 4n), wave tile 64x32, acc[4][2] -> 32 acc regs.
// Rationale (R4 counters): 2-barrier loop is latency-bound at 3.5 waves/SIMD
// (wall 2176 cyc/step vs max pipe 768); shrinking the wave tile halves the
// accumulator so 3 blocks/CU x 8 waves = 6 waves/SIMD fit. Design regs ~75;
// (512,6) caps at 85 -- comfortable margin (R3 lesson: never cap below need).
// Same LDS layout + XOR swizzle + staging as the proven 232us kernel.
__global__ __launch_bounds__(512, 6) void screen_kernel(
    const _Float16* __restrict__ z16, const _Float16* __restrict__ cb16,
    const float* __restrict__ e_sq,
    unsigned long long* __restrict__ keys, unsigned* __restrict__ sec2) {
    __shared__ _Float16 zt[128 * 64];   // 16 KB (reused for epilogue)
    __shared__ _Float16 ct[128 * 64];   // 16 KB

    const int tid = threadIdx.x;
    const int by = blockIdx.x;   // row tile (128)
    const int bx = blockIdx.y;   // code tile (128)
    const int lane = tid & 63, wid = tid >> 6;
    const int wm = wid >> 2, wn = wid & 3;      // 2 x 4 wave grid
    const int lr = lane & 15, lq = lane >> 4;

    // staging pointers: granule g = (r*8+wid)*64+lane; row=g>>3, kq=g&7;
    // source carries XOR swizzle so ds_read_b128 frags stay conflict-free.
    const _Float16* zsrc[2]; const _Float16* csrc[2];
    #pragma unroll
    for (int r = 0; r < 2; r++) {
        int g = (r * 8 + wid) * 64 + lane;
        int row = g >> 3, kq = g & 7;
        zsrc[r] = z16 + (size_t)(by * 128 + row) * DDIM + ((kq ^ (row & 7)) << 3);
        csrc[r] = cb16 + (size_t)(bx * 128 + row) * DDIM + ((kq ^ (row & 7)) << 3);
    }

    floatx4 acc[4][2];
    #pragma unroll
    for (int i = 0; i < 4; i++)
        #pragma unroll
        for (int j = 0; j < 2; j++) acc[i][j] = floatx4{0.f, 0.f, 0.f, 0.f};

    for (int kc = 0; kc < DDIM; kc += 64) {
        #pragma unroll
        for (int r = 0; r < 2; r++) load_lds16(zsrc[r] + kc, &zt[(r * 8 + wid) * 512]);
        #pragma unroll
        for (int r = 0; r < 2; r++) load_lds16(csrc[r] + kc, &ct[(r * 8 + wid) * 512]);
        __syncthreads();
        #pragma unroll
        for (int kk = 0; kk < 2; kk++) {
            half8 bv[2];
            #pragma unroll
            for (int nt = 0; nt < 2; nt++) {
                int row = wn * 32 + nt * 16 + lr;
                bv[nt] = *(const half8*)&ct[row * 64 + (((kk * 4 + lq) ^ (row & 7)) << 3)];
            }
            #pragma unroll
            for (int mt = 0; mt < 4; mt++) {
                int row = wm * 64 + mt * 16 + lr;
                half8 av = *(const half8*)&zt[row * 64 + (((kk * 4 + lq) ^ (row & 7)) << 3)];
                acc[mt][0] = __builtin_amdgcn_mfma_f32_16x16x32_f16(av, bv[0], acc[mt][0], 0, 0, 0);
                acc[mt][1] = __builtin_amdgcn_mfma_f32_16x16x32_f16(av, bv[1], acc[mt][1], 0, 0, 0);
            }
        }
        __syncthreads();
    }

    // epilogue scratch aliased onto zt (all ds_reads drained by loop-end barrier)
    float* eb_d1 = (float*)zt;            // [4][128]
    int*   eb_c1 = (int*)zt + 512;        // [4][128]
    float* eb_d2 = (float*)zt + 1024;     // [4][128]

    float es[2];
    #pragma unroll
    for (int nt = 0; nt < 2; nt++) es[nt] = e_sq[bx * 128 + wn * 32 + nt * 16 + lr];

    #pragma unroll
    for (int mt = 0; mt < 4; mt++) {
        #pragma unroll
        for (int r = 0; r < 4; r++) {
            float dA = fmaf(-2.0f, acc[mt][0][r], es[0]);
            int   cA = bx * 128 + wn * 32 + lr;
            float dB = fmaf(-2.0f, acc[mt][1][r], es[1]);
            int   cB = bx * 128 + wn * 32 + 16 + lr;
            bool bbet = (dB < dA) || (dB == dA && cB < cA);
            float d1 = bbet ? dB : dA; int c1 = bbet ? cB : cA;
            float d2 = bbet ? dA : dB;
            #pragma unroll
            for (int off = 1; off < 16; off <<= 1) {
                float od1 = __shfl_xor(d1, off);
                int   oc1 = __shfl_xor(c1, off);
                float od2 = __shfl_xor(d2, off);
                bool better = (od1 < d1) || (od1 == d1 && oc1 < c1);
                if (better) { d2 = fminf(d1, od2); d1 = od1; c1 = oc1; }
                else        { d2 = fminf(d2, od1); }
            }
            if (lr == 0) {
                int row = wm * 64 + mt * 16 + lq * 4 + r;
                eb_d1[wn * 128 + row] = d1; eb_c1[wn * 128 + row] = c1; eb_d2[wn * 128 + row] = d2;
            }
        }
    }
    __syncthreads();
    if (tid < 128) {
        float d1 = eb_d1[tid], d2 = eb_d2[tid]; int c1 = eb_c1[tid];
        #pragma unroll
        for (int w = 1; w < 4; w++) {
            float e1 = eb_d1[w * 128 + tid], e2 = eb_d2[w * 128 + tid]; int ec = eb_c1[w * 128 + tid];
            bool bet = (e1 < d1) || (e1 == d1 && ec < c1);
            if (bet) { d2 = fminf(d1, e2); d1 = e1; c1 = ec; }
            else     { d2 = fminf(d2, e1); }
        }
        unsigned long long key = ((unsigned long long)enc_f(d1) << 32) | (unsigned)c1;
        int row_g = by * 128 + tid;
        unsigned long long old = atomicMin(&keys[row_g], key);
        // second-best candidate: if we displaced old best, old's dist is a cand;
        // else our d1 is a cand. d2 always a cand. (fminf(NaN,x)=x handles init.)
        float cand = (key < old) ? fminf(dec_key(old), d2) : fminf(d1, d2);
        atomicMin(&sec2[row_g], enc_f(cand));
    }
}

// ---------------- merge: flag near-ties ----------------
__global__ void merge_kernel(unsigned long long* __restrict__ keys,
                             const unsigned* __restrict__ sec2,
                             int* __restrict__ flagcnt, int* __restrict__ flaglist) {
    int row = blockIdx.x * 256 + threadIdx.x;
    unsigned long long kb = keys[row];
    float best = dec_key(kb);
    float sec  = dec32(sec2[row]);
    if (sec - best < TAU) {
        int pos = atomicAdd(flagcnt, 1);
        if (pos < RCAP) { flaglist[pos] = row; keys[row] = ~0ULL; }
    }
}

// ---------------- rescore v2: exact fp32 over flagged rows ----------------
// Tile: 128 codes x 64 rows per block. k-major transposed LDS so inner-loop
// reads are ds_read_b128 (3 per k for 32 FMA) instead of 8 scalar b32 per 16.
// Per-thread 8 codes x 4 rows. fmaf chain stays k-ascending (bit-identical).
__global__ __launch_bounds__(256) void rescore_kernel(
    const float* __restrict__ z, const float* __restrict__ cb,
    const float* __restrict__ e_sq, const int* __restrict__ flagcnt,
    const int* __restrict__ flaglist, unsigned long long* __restrict__ keys) {
    int n = *flagcnt; n = min(n, RCAP);
    int base = blockIdx.y * 64;
    if (base >= n) return;
    __shared__ float ech[64][132];   // [k][code]  33.8 KB
    __shared__ float zch[64][68];    // [k][row]   17.4 KB
    __shared__ int ridx[64];
    const int tid = threadIdx.x;
    const int bx = blockIdx.x;
    if (tid < 64) ridx[tid] = flaglist[min(base + tid, n - 1)];
    __syncthreads();

    const int tc = tid & 15;   // 16 code-groups of 8
    const int tg = tid >> 4;   // 16 row-groups of 4

    // e_sq for this thread's 8 codes (registers, read once)
    float es[8];
    #pragma unroll
    for (int c = 0; c < 8; c++) es[c] = e_sq[bx * 128 + tc * 8 + c];

    float acc[4][8] = {};
    for (int kc = 0; kc < DDIM; kc += 64) {
        // stage cb -> ech transposed: 2048 float4 loads, 256 thr x 8
        #pragma unroll
        for (int l = 0; l < 8; l++) {
            int gi = tid + 256 * l;
            int code = gi >> 4, q = gi & 15;
            float4 v = *(const float4*)&cb[(size_t)(bx * 128 + code) * DDIM + kc + q * 4];
            ech[q * 4 + 0][code] = v.x; ech[q * 4 + 1][code] = v.y;
            ech[q * 4 + 2][code] = v.z; ech[q * 4 + 3][code] = v.w;
        }
        // stage z -> zch transposed: 1024 float4 loads, 256 thr x 4 (row-gather)
        #pragma unroll
        for (int l = 0; l < 4; l++) {
            int gi = tid + 256 * l;
            int row = gi >> 4, q = gi & 15;
            float4 v = *(const float4*)&z[(size_t)ridx[row] * DDIM + kc + q * 4];
            zch[q * 4 + 0][row] = v.x; zch[q * 4 + 1][row] = v.y;
            zch[q * 4 + 2][row] = v.z; zch[q * 4 + 3][row] = v.w;
        }
        __syncthreads();
        for (int k = 0; k < 64; k++) {
            const float4 b0 = *(const float4*)&ech[k][tc * 8];
            const float4 b1 = *(const float4*)&ech[k][tc * 8 + 4];
            const float4 a  = *(const float4*)&zch[k][tg * 4];
            const float ar[4] = {a.x, a.y, a.z, a.w};
            const float br[8] = {b0.x, b0.y, b0.z, b0.w, b1.x, b1.y, b1.z, b1.w};
            #pragma unroll
            for (int r = 0; r < 4; r++)
                #pragma unroll
                for (int c = 0; c < 8; c++)
                    acc[r][c] = fmaf(ar[r], br[c], acc[r][c]);
        }
        __syncthreads();
    }

    // per-thread best over its 8 codes, per row; then block reduce over 16 tc
    unsigned long long (*redk)[17] = (unsigned long long (*)[17])&ech[0][0];  // alias (64x17 u64)
    #pragma unroll
    for (int r = 0; r < 4; r++) {
        unsigned long long bk = ~0ULL;
        #pragma unroll
        for (int c = 0; c < 8; c++) {
            int code = bx * 128 + tc * 8 + c;
            float d = fmaf(-2.0f, acc[r][c], es[c]);
            unsigned long long key = ((unsigned long long)enc_f(d) << 32) | (unsigned)code;
            bk = (key < bk) ? key : bk;
        }
        redk[tg * 4 + r][tc] = bk;
    }
    __syncthreads();
    if (tid < 64) {
        unsigned long long b = redk[tid][0];
        #pragma unroll
        for (int t = 1; t < 16; t++) {
            unsigned long long v = redk[tid][t];
            b = (v < b) ? v : b;
        }
        atomicMin(&keys[ridx[tid]], b);
    }
}

// ---------------- C0: z_out, loss partials, counts, idx list (2 rows/block) ------------
__global__ __launch_bounds__(256) void zout_loss_kernel(
    const float* __restrict__ z, const float* __restrict__ cb,
    const unsigned long long* __restrict__ keys,
    float* __restrict__ out, int* __restrict__ cnt,
    int* __restrict__ idxs, float* __restrict__ lossp) {
    const int tid = threadIdx.x;
    const int sub = tid >> 7;                 // 0/1: which row of this block
    const int t   = tid & 127;
    const int row = blockIdx.x * 2 + sub;
    const int idx = (int)(unsigned int)(keys[row] & 0xFFFFFFFFull);

    const float4 zv = ((const float4*)(z  + (size_t)row * DDIM))[t];
    const float4 ev = ((const float4*)(cb + (size_t)idx * DDIM))[t];
    ((float4*)(out + O_Z + (size_t)row * DDIM))[t] = ev;

    float dx = zv.x - ev.x, dy = zv.y - ev.y, dz = zv.z - ev.z, dw = zv.w - ev.w;
    float s = dx*dx + dy*dy + dz*dz + dw*dw;

    #pragma unroll
    for (int o = 32; o > 0; o >>= 1) s += __shfl_down(s, o);
    __shared__ float red[4];
    if ((tid & 63) == 0) red[tid >> 6] = s;
    __syncthreads();
    if (t == 0) {   // tid 0 (sub 0) and tid 128 (sub 1)
        atomicAdd(&lossp[row & 63], red[sub * 2] + red[sub * 2 + 1]);
        atomicAdd(&cnt[idx], 1);
        idxs[row] = idx;
    }
}

// ---------------- C2: scan counts -> offsets; new_ema_cluster_size; loss finalize ------
__global__ __launch_bounds__(256) void scan_kernel(
    const int* __restrict__ cnt, const float* __restrict__ ema_cs,
    const float* __restrict__ lossp,
    float* __restrict__ out, int* __restrict__ offs, int* __restrict__ curs) {
    __shared__ int tot[256];
    const int t = threadIdx.x;
    // loss finalize folded in (wave 0 only; independent of the scan below)
    if (t < 64) {
        float s = lossp[t];
        #pragma unroll
        for (int o = 32; o > 0; o >>= 1) s += __shfl_down(s, o);
        if (t == 0) out[O_LOSS] = s * (BETA / (float)DDIM);
    }
    const int base = t * 32;
    int local[32]; int s = 0;
    #pragma unroll
    for (int j = 0; j < 32; j++) { local[j] = cnt[base + j]; s += local[j]; }
    tot[t] = s;
    __syncthreads();
    for (int off = 1; off < 256; off <<= 1) {
        int v = (t >= off) ? tot[t - off] : 0;
        __syncthreads();
        tot[t] += v;
        __syncthreads();
    }
    int run = tot[t] - s;  // exclusive prefix
    #pragma unroll
    for (int j = 0; j < 32; j++) {
        offs[base + j] = run; curs[base + j] = run;
        out[O_CS + base + j] = DECAY * ema_cs[base + j] + ONE_MINUS_DECAY * (float)local[j];
        run += local[j];
    }
}

// ---------------- C3: fill rowlist ----------------
__global__ void fill_kernel(const int* __restrict__ idxs, int* __restrict__ curs,
                            int* __restrict__ rowlist) {
    int row = blockIdx.x * 256 + threadIdx.x;
    int idx = idxs[row];
    int pos = atomicAdd(&curs[idx], 1);
    rowlist[pos] = row;
}

// ---------------- C4: per-code EMA avg + codebook update ----------------
// 1 wave per code: gather its rows from z, fold decay + divide + active mask.
__global__ __launch_bounds__(256) void code_update_kernel(
    const float* __restrict__ z, const float* __restrict__ cb,
    const float* __restrict__ ema_cs, const float* __restrict__ ema_avg,
    const int* __restrict__ cnt, const int* __restrict__ offs,
    const int* __restrict__ rowlist, float* __restrict__ out) {
    const int lane = threadIdx.x & 63;
    const int k = blockIdx.x * 4 + (threadIdx.x >> 6);
    const int n = cnt[k], off = offs[k];
    float4 a0 = {0.f,0.f,0.f,0.f}, a1 = {0.f,0.f,0.f,0.f};
    for (int r = 0; r < n; r++) {
        int row = rowlist[off + r];
        const float4* zp = (const float4*)(z + (size_t)row * DDIM) + lane * 2;
        float4 v0 = zp[0], v1 = zp[1];
        a0.x += v0.x; a0.y += v0.y; a0.z += v0.z; a0.w += v0.w;
        a1.x += v1.x; a1.y += v1.y; a1.z += v1.z; a1.w += v1.w;
    }
    const float4* ep = (const float4*)(ema_avg + (size_t)k * DDIM) + lane * 2;
    float4 e0 = ep[0], e1 = ep[1];
    float4 n0, n1;
    n0.x = DECAY * e0.x + ONE_MINUS_DECAY * a0.x; n0.y = DECAY * e0.y + ONE_MINUS_DECAY * a0.y;
    n0.z = DECAY * e0.z + ONE_MINUS_DECAY * a0.z; n0.w = DECAY * e0.w + ONE_MINUS_DECAY * a0.w;
    n1.x = DECAY * e1.x + ONE_MINUS_DECAY * a1.x; n1.y = DECAY * e1.y + ONE_MINUS_DECAY * a1.y;
    n1.z = DECAY * e1.z + ONE_MINUS_DECAY * a1.z; n1.w = DECAY * e1.w + ONE_MINUS_DECAY * a1.w;
    ((float4*)(out + O_AVG + (size_t)k * DDIM))[lane * 2]     = n0;
    ((float4*)(out + O_AVG + (size_t)k * DDIM))[lane * 2 + 1] = n1;

    float ncs = DECAY * ema_cs[k] + ONE_MINUS_DECAY * (float)n;
    float inv = 1.0f / (ncs + EMA_EPS);
    float4 c0, c1;
    if (n > 0) {
        c0.x = n0.x * inv; c0.y = n0.y * inv; c0.z = n0.z * inv; c0.w = n0.w * inv;
        c1.x = n1.x * inv; c1.y = n1.y * inv; c1.z = n1.z * inv; c1.w = n1.w * inv;
    } else {
        const float4* cp = (const float4*)(cb + (size_t)k * DDIM) + lane * 2;
        c0 = cp[0]; c1 = cp[1];
    }
    ((float4*)(out + O_CB + (size_t)k * DDIM))[lane * 2]     = c0;
    ((float4*)(out + O_CB + (size_t)k * DDIM))[lane * 2 + 1] = c1;
}

extern "C" void kernel_launch(void* const* d_in, const int* in_sizes, int n_in,
                              void* d_out, int out_size, void* d_ws, size_t ws_size,
                              hipStream_t stream) {
    const float* z       = (const float*)d_in[0];
    const float* cb      = (const float*)d_in[1];
    const float* ema_cs  = (const float*)d_in[2];
    const float* ema_avg = (const float*)d_in[3];
    float* out = (float*)d_out;

    int* cnt       = (int*)((char*)d_ws + WS_CNT);
    float* e_sq    = (float*)((char*)d_ws + WS_ESQ);
    int* flagcnt   = (int*)((char*)d_ws + WS_FLAGCNT);
    int* flaglist  = (int*)((char*)d_ws + WS_FLAGLIST);
    unsigned long long* keys = (unsigned long long*)((char*)d_ws + WS_KEYS);
    unsigned* sec2 = (unsigned*)((char*)d_ws + WS_SEC2);
    float* lossp   = (float*)((char*)d_ws + WS_LOSSP);
    int* idxs      = (int*)((char*)d_ws + WS_IDXS);
    int* offs      = (int*)((char*)d_ws + WS_OFFS);
    int* curs      = (int*)((char*)d_ws + WS_CURS);
    int* rowlist   = (int*)((char*)d_ws + WS_ROWLIST);
    _Float16* z16  = (_Float16*)((char*)d_ws + WS_Z16);
    _Float16* cb16 = (_Float16*)((char*)d_ws + WS_CB16);

    cvtz_kernel<<<N_ROWS * DDIM / 8 / 256, 256, 0, stream>>>(z, z16, keys, sec2, lossp, flagcnt);
    cvtcb_kernel<<<KCODES, 64, 0, stream>>>(cb, cb16, e_sq, cnt);
    screen_kernel<<<dim3(N_ROWS / 128, KCODES / 128), 512, 0, stream>>>(z16, cb16, e_sq, keys, sec2);
    merge_kernel<<<N_ROWS / 256, 256, 0, stream>>>(keys, sec2, flagcnt, flaglist);
    rescore_kernel<<<dim3(KCODES / 128, RCAP / 64), 256, 0, stream>>>(z, cb, e_sq, flagcnt, flaglist, keys);
    zout_loss_kernel<<<N_ROWS / 2, 256, 0, stream>>>(z, cb, keys, out, cnt, idxs, lossp);
    scan_kernel<<<1, 256, 0, stream>>>(cnt, ema_cs, lossp, out, offs, curs);
    fill_kernel<<<N_ROWS / 256, 256, 0, stream>>>(idxs, curs, rowlist);
    code_update_kernel<<<KCODES / 4, 256, 0, stream>>>(z, cb, ema_cs, ema_avg, cnt, offs, rowlist, out);
}

// Round 6
// 661.088 us; speedup vs baseline: 1.0870x; 1.0870x over previous
//
#include <hip/hip_runtime.h>
#include <hip/hip_bf16.h>

// Problem constants
#define N_ROWS 16384   // 8*2048
#define DDIM   512
#define KCODES 8192
#define BETA   0.25f
#define DECAY  0.99f
#define ONE_MINUS_DECAY 0.01f
#define EMA_EPS 1e-5f

// Output layout (floats, concatenated in reference return order)
#define O_Z    0                 // z_out: 8388608
#define O_LOSS 8388608           // vq_loss: 1
#define O_CS   8388609           // new_ema_cluster_size: 8192
#define O_AVG  8396801           // new_ema_embed_avg: 4194304
#define O_CB   12591105          // new_codebook: 4194304

// Workspace layout (bytes), all 256-aligned; total ~25.5 MB
#define WS_CNT      0            // int[8192]            32 KB
#define WS_ESQ      32768        // float[8192]          32 KB
#define WS_FLAGCNT  65536        // int (+pad)           256 B
#define WS_FLAGLIST 65792        // int[2048]            8 KB
#define WS_KEYS     73984        // u64[16384]           128 KB
#define WS_SEC2     205056       // u32[16384]           64 KB
#define WS_LOSSP    270592       // float[64]            256 B
#define WS_IDXS     270848       // int[16384]           64 KB
#define WS_OFFS     336384       // int[8192]            32 KB
#define WS_CURS     369152       // int[8192]            32 KB
#define WS_ROWLIST  401920       // int[16384]           64 KB
#define WS_Z16      467456       // f16[16384*512]       16 MB
#define WS_CB16     17244672     // f16[8192*512]        8 MB   (end ~25.6 MB)

#define TAU  0.35f
#define RCAP 2048

typedef _Float16 half8  __attribute__((ext_vector_type(8)));
typedef float    floatx4 __attribute__((ext_vector_type(4)));

// monotone float<->u32 (ascending order preserved)
__device__ __forceinline__ unsigned enc_f(float d) {
    unsigned ub = __float_as_uint(d);
    return (ub & 0x80000000u) ? ~ub : (ub | 0x80000000u);
}
__device__ __forceinline__ float dec32(unsigned ub) {
    return __uint_as_float((ub & 0x80000000u) ? (ub ^ 0x80000000u) : ~ub);
}
__device__ __forceinline__ float dec_key(unsigned long long k) {
    return dec32((unsigned)(k >> 32));
}

__device__ __forceinline__ float4 pack8_f16(float4 a, float4 b) {
    auto p0 = __builtin_amdgcn_cvt_pkrtz(a.x, a.y);
    auto p1 = __builtin_amdgcn_cvt_pkrtz(a.z, a.w);
    auto p2 = __builtin_amdgcn_cvt_pkrtz(b.x, b.y);
    auto p3 = __builtin_amdgcn_cvt_pkrtz(b.z, b.w);
    float4 r;
    r.x = __builtin_bit_cast(float, p0);
    r.y = __builtin_bit_cast(float, p1);
    r.z = __builtin_bit_cast(float, p2);
    r.w = __builtin_bit_cast(float, p3);
    return r;
}

// global->LDS direct DMA, 16 B per lane. LDS dest = wave-uniform base + lane*16.
__device__ __forceinline__ void load_lds16(const void* g, void* l) {
    __builtin_amdgcn_global_load_lds(
        (const __attribute__((address_space(1))) unsigned int*)g,
        (__attribute__((address_space(3))) unsigned int*)l, 16, 0, 0);
}

// ---------------- cvtz: z fp32 -> f16, plus workspace init (replaces 4 memsets) --------
__global__ __launch_bounds__(256) void cvtz_kernel(const float* __restrict__ z,
                                                   _Float16* __restrict__ z16,
                                                   unsigned long long* __restrict__ keys,
                                                   unsigned* __restrict__ sec2,
                                                   float* __restrict__ lossp,
                                                   int* __restrict__ flagcnt) {
    size_t i = (size_t)blockIdx.x * 256 + threadIdx.x;   // 8 elems per thread
    const float4* p = (const float4*)z + 2 * i;
    ((float4*)z16)[i] = pack8_f16(p[0], p[1]);
    // init section: screen/merge/zout consumers all launch after cvtz in-stream
    if (i < N_ROWS) { keys[i] = ~0ULL; sec2[i] = 0xFFFFFFFFu; }
    if (i < 64) lossp[i] = 0.0f;
    if (i == 0) *flagcnt = 0;
}

// ---------------- cvtcb: cb fp32 -> f16 + e_sq + cnt zero ----------------
__global__ __launch_bounds__(64) void cvtcb_kernel(const float* __restrict__ cb,
                                                   _Float16* __restrict__ cb16,
                                                   float* __restrict__ e_sq,
                                                   int* __restrict__ cnt) {
    int k = blockIdx.x;
    int t = threadIdx.x;
    const float4* r = (const float4*)(cb + (size_t)k * DDIM);
    float4 a = r[2 * t], b = r[2 * t + 1];
    ((float4*)(cb16 + (size_t)k * DDIM))[t] = pack8_f16(a, b);
    float s = a.x*a.x + a.y*a.y + a.z*a.z + a.w*a.w
            + b.x*b.x + b.y*b.y + b.z*b.z + b.w*b.w;
    #pragma unroll
    for (int o = 32; o > 0; o >>= 1) s += __shfl_down(s, o);
    if (t == 0) { e_sq[k] = s; cnt[k] = 0; }
}

// ---------------- screen v4: v2 (proven 232us) + hoisted LDS addressing ----------------
// 256 thr (4 waves, 2x2), wave tile 64x64, acc[4][4]. LDS 32 KB, XOR swizzle.
// R5 diagnosis: v2 was VALU-issue-bound (VALUBusy 48% = ~150 addr insts/wave/step,
// all kc-invariant). Fix: 4 loop-invariant fragment base pointers (zt/ct x kk0/kk1);
// mt/nt strides are constant 2048 B (row&7 == lane&7 for all fragment rows) so they
// fold into ds_read_b128 imm offsets; kc loop fully unrolled folds staging offsets.
// NOTE: (256,4) is the register floor -- (256,5) spills acc (R3: +55% dur).
__global__ __launch_bounds__(256, 4) void screen_kernel(
    const _Float16* __restrict__ z16, const _Float16* __restrict__ cb16,
    const float* __restrict__ e_sq,
    unsigned long long* __restrict__ keys, unsigned* __restrict__ sec2) {
    __shared__ _Float16 zt[128 * 64];   // 16 KB (reused for epilogue)
    __shared__ _Float16 ct[128 * 64];   // 16 KB

    const int tid = threadIdx.x;
    const int by = blockIdx.x;   // row tile (128)
    const int bx = blockIdx.y;   // code tile (128)
    const int lane = tid & 63, wid = tid >> 6;
    const int wm = wid & 1, wn = wid >> 1;
    const int lr = lane & 15, lq = lane >> 4;
    const int r7 = lane & 7;

    // staging pointers: granule g = (r*4+wid)*64+lane; row=g>>3, kq=g&7;
    // source carries XOR swizzle so ds_read_b128 frags stay conflict-free.
    const _Float16* zsrc[4]; const _Float16* csrc[4];
    #pragma unroll
    for (int r = 0; r < 4; r++) {
        int g = (r * 4 + wid) * 64 + lane;
        int row = g >> 3, kq = g & 7;
        zsrc[r] = z16 + (size_t)(by * 128 + row) * DDIM + ((kq ^ (row & 7)) << 3);
        csrc[r] = cb16 + (size_t)(bx * 128 + row) * DDIM + ((kq ^ (row & 7)) << 3);
    }

    // kc-invariant LDS fragment bases. Fragment row = w*64 + mt*16 + lr, so
    // row&7 == lane&7 (r7) for ALL mt -> swizzle slot is mt-independent and the
    // mt stride is exactly 16 rows * 128 B = 2048 B (imm-foldable).
    const _Float16* za[2]; const _Float16* ca[2];
    za[0] = &zt[(wm * 64 + lr) * 64 + ((lq ^ r7) << 3)];
    za[1] = &zt[(wm * 64 + lr) * 64 + (((4 + lq) ^ r7) << 3)];
    ca[0] = &ct[(wn * 64 + lr) * 64 + ((lq ^ r7) << 3)];
    ca[1] = &ct[(wn * 64 + lr) * 64 + (((4 + lq) ^ r7) << 3)];

    floatx4 acc[4][4];
    #pragma unroll
    for (int i = 0; i < 4; i++)
        #pragma unroll
        for (int j = 0; j < 4; j++) acc[i][j] = floatx4{0.f, 0.f, 0.f, 0.f};

    #pragma unroll
    for (int t = 0; t < 8; t++) {
        const int kc = t * 64;
        #pragma unroll
        for (int r = 0; r < 4; r++) load_lds16(zsrc[r] + kc, &zt[(r * 4 + wid) * 512]);
        #pragma unroll
        for (int r = 0; r < 4; r++) load_lds16(csrc[r] + kc, &ct[(r * 4 + wid) * 512]);
        __syncthreads();
        #pragma unroll
        for (int kk = 0; kk < 2; kk++) {
            half8 av[4];
            #pragma unroll
            for (int mt = 0; mt < 4; mt++)
                av[mt] = *(const half8*)(za[kk] + mt * 1024);
            #pragma unroll
            for (int nt = 0; nt < 4; nt++) {
                half8 bv = *(const half8*)(ca[kk] + nt * 1024);
                #pragma unroll
                for (int mt = 0; mt < 4; mt++)
                    acc[mt][nt] = __builtin_amdgcn_mfma_f32_16x16x32_f16(av[mt], bv, acc[mt][nt], 0, 0, 0);
            }
        }
        __syncthreads();
    }

    // epilogue scratch aliased onto zt (all ds_reads drained by loop-end barrier)
    float* eb_d1 = (float*)zt;            // [2][128]
    int*   eb_c1 = (int*)zt + 256;        // [2][128]
    float* eb_d2 = (float*)zt + 512;      // [2][128]

    float es[4];
    #pragma unroll
    for (int nt = 0; nt < 4; nt++) es[nt] = e_sq[bx * 128 + wn * 64 + nt * 16 + lr];

    #pragma unroll
    for (int mt = 0; mt < 4; mt++) {
        #pragma unroll
        for (int r = 0; r < 4; r++) {
            float d1 = 1e30f, d2 = 1e30f; int c1 = 0x7FFFFFFF;
            #pragma unroll
            for (int nt = 0; nt < 4; nt++) {
                float d = fmaf(-2.0f, acc[mt][nt][r], es[nt]);
                int c = bx * 128 + wn * 64 + nt * 16 + lr;
                bool better = (d < d1) || (d == d1 && c < c1);
                if (better) { d2 = d1; d1 = d; c1 = c; }
                else        { d2 = fminf(d2, d); }
            }
            #pragma unroll
            for (int off = 1; off < 16; off <<= 1) {
                float od1 = __shfl_xor(d1, off);
                int   oc1 = __shfl_xor(c1, off);
                float od2 = __shfl_xor(d2, off);
                bool better = (od1 < d1) || (od1 == d1 && oc1 < c1);
                if (better) { d2 = fminf(d1, od2); d1 = od1; c1 = oc1; }
                else        { d2 = fminf(d2, od1); }
            }
            if (lr == 0) {
                int row = wm * 64 + mt * 16 + lq * 4 + r;
                eb_d1[wn * 128 + row] = d1; eb_c1[wn * 128 + row] = c1; eb_d2[wn * 128 + row] = d2;
            }
        }
    }
    __syncthreads();
    if (tid < 128) {
        float d1a = eb_d1[tid],       d2a = eb_d2[tid];       int c1a = eb_c1[tid];
        float d1b = eb_d1[128 + tid], d2b = eb_d2[128 + tid]; int c1b = eb_c1[128 + tid];
        bool bbet = (d1b < d1a) || (d1b == d1a && c1b < c1a);
        float d1 = bbet ? d1b : d1a; int c1 = bbet ? c1b : c1a;
        float d2 = bbet ? fminf(d1a, d2b) : fminf(d2a, d1b);
        unsigned long long key = ((unsigned long long)enc_f(d1) << 32) | (unsigned)c1;
        int row_g = by * 128 + tid;
        unsigned long long old = atomicMin(&keys[row_g], key);
        // second-best candidate: if we displaced old best, old's dist is a cand;
        // else our d1 is a cand. d2 always a cand. (fminf(NaN,x)=x handles init.)
        float cand = (key < old) ? fminf(dec_key(old), d2) : fminf(d1, d2);
        atomicMin(&sec2[row_g], enc_f(cand));
    }
}

// ---------------- merge: flag near-ties ----------------
__global__ void merge_kernel(unsigned long long* __restrict__ keys,
                             const unsigned* __restrict__ sec2,
                             int* __restrict__ flagcnt, int* __restrict__ flaglist) {
    int row = blockIdx.x * 256 + threadIdx.x;
    unsigned long long kb = keys[row];
    float best = dec_key(kb);
    float sec  = dec32(sec2[row]);
    if (sec - best < TAU) {
        int pos = atomicAdd(flagcnt, 1);
        if (pos < RCAP) { flaglist[pos] = row; keys[row] = ~0ULL; }
    }
}

// ---------------- rescore v2: exact fp32 over flagged rows ----------------
// Tile: 128 codes x 64 rows per block. k-major transposed LDS so inner-loop
// reads are ds_read_b128 (3 per k for 32 FMA) instead of 8 scalar b32 per 16.
// Per-thread 8 codes x 4 rows. fmaf chain stays k-ascending (bit-identical).
__global__ __launch_bounds__(256) void rescore_kernel(
    const float* __restrict__ z, const float* __restrict__ cb,
    const float* __restrict__ e_sq, const int* __restrict__ flagcnt,
    const int* __restrict__ flaglist, unsigned long long* __restrict__ keys) {
    int n = *flagcnt; n = min(n, RCAP);
    int base = blockIdx.y * 64;
    if (base >= n) return;
    __shared__ float ech[64][132];   // [k][code]  33.8 KB
    __shared__ float zch[64][68];    // [k][row]   17.4 KB
    __shared__ int ridx[64];
    const int tid = threadIdx.x;
    const int bx = blockIdx.x;
    if (tid < 64) ridx[tid] = flaglist[min(base + tid, n - 1)];
    __syncthreads();

    const int tc = tid & 15;   // 16 code-groups of 8
    const int tg = tid >> 4;   // 16 row-groups of 4

    // e_sq for this thread's 8 codes (registers, read once)
    float es[8];
    #pragma unroll
    for (int c = 0; c < 8; c++) es[c] = e_sq[bx * 128 + tc * 8 + c];

    float acc[4][8] = {};
    for (int kc = 0; kc < DDIM; kc += 64) {
        // stage cb -> ech transposed: 2048 float4 loads, 256 thr x 8
        #pragma unroll
        for (int l = 0; l < 8; l++) {
            int gi = tid + 256 * l;
            int code = gi >> 4, q = gi & 15;
            float4 v = *(const float4*)&cb[(size_t)(bx * 128 + code) * DDIM + kc + q * 4];
            ech[q * 4 + 0][code] = v.x; ech[q * 4 + 1][code] = v.y;
            ech[q * 4 + 2][code] = v.z; ech[q * 4 + 3][code] = v.w;
        }
        // stage z -> zch transposed: 1024 float4 loads, 256 thr x 4 (row-gather)
        #pragma unroll
        for (int l = 0; l < 4; l++) {
            int gi = tid + 256 * l;
            int row = gi >> 4, q = gi & 15;
            float4 v = *(const float4*)&z[(size_t)ridx[row] * DDIM + kc + q * 4];
            zch[q * 4 + 0][row] = v.x; zch[q * 4 + 1][row] = v.y;
            zch[q * 4 + 2][row] = v.z; zch[q * 4 + 3][row] = v.w;
        }
        __syncthreads();
        for (int k = 0; k < 64; k++) {
            const float4 b0 = *(const float4*)&ech[k][tc * 8];
            const float4 b1 = *(const float4*)&ech[k][tc * 8 + 4];
            const float4 a  = *(const float4*)&zch[k][tg * 4];
            const float ar[4] = {a.x, a.y, a.z, a.w};
            const float br[8] = {b0.x, b0.y, b0.z, b0.w, b1.x, b1.y, b1.z, b1.w};
            #pragma unroll
            for (int r = 0; r < 4; r++)
                #pragma unroll
                for (int c = 0; c < 8; c++)
                    acc[r][c] = fmaf(ar[r], br[c], acc[r][c]);
        }
        __syncthreads();
    }

    // per-thread best over its 8 codes, per row; then block reduce over 16 tc
    unsigned long long (*redk)[17] = (unsigned long long (*)[17])&ech[0][0];  // alias (64x17 u64)
    #pragma unroll
    for (int r = 0; r < 4; r++) {
        unsigned long long bk = ~0ULL;
        #pragma unroll
        for (int c = 0; c < 8; c++) {
            int code = bx * 128 + tc * 8 + c;
            float d = fmaf(-2.0f, acc[r][c], es[c]);
            unsigned long long key = ((unsigned long long)enc_f(d) << 32) | (unsigned)code;
            bk = (key < bk) ? key : bk;
        }
        redk[tg * 4 + r][tc] = bk;
    }
    __syncthreads();
    if (tid < 64) {
        unsigned long long b = redk[tid][0];
        #pragma unroll
        for (int t = 1; t < 16; t++) {
            unsigned long long v = redk[tid][t];
            b = (v < b) ? v : b;
        }
        atomicMin(&keys[ridx[tid]], b);
    }
}

// ---------------- C0: z_out, loss partials, counts, idx list (2 rows/block) ------------
__global__ __launch_bounds__(256) void zout_loss_kernel(
    const float* __restrict__ z, const float* __restrict__ cb,
    const unsigned long long* __restrict__ keys,
    float* __restrict__ out, int* __restrict__ cnt,
    int* __restrict__ idxs, float* __restrict__ lossp) {
    const int tid = threadIdx.x;
    const int sub = tid >> 7;                 // 0/1: which row of this block
    const int t   = tid & 127;
    const int row = blockIdx.x * 2 + sub;
    const int idx = (int)(unsigned int)(keys[row] & 0xFFFFFFFFull);

    const float4 zv = ((const float4*)(z  + (size_t)row * DDIM))[t];
    const float4 ev = ((const float4*)(cb + (size_t)idx * DDIM))[t];
    ((float4*)(out + O_Z + (size_t)row * DDIM))[t] = ev;

    float dx = zv.x - ev.x, dy = zv.y - ev.y, dz = zv.z - ev.z, dw = zv.w - ev.w;
    float s = dx*dx + dy*dy + dz*dz + dw*dw;

    #pragma unroll
    for (int o = 32; o > 0; o >>= 1) s += __shfl_down(s, o);
    __shared__ float red[4];
    if ((tid & 63) == 0) red[tid >> 6] = s;
    __syncthreads();
    if (t == 0) {   // tid 0 (sub 0) and tid 128 (sub 1)
        atomicAdd(&lossp[row & 63], red[sub * 2] + red[sub * 2 + 1]);
        atomicAdd(&cnt[idx], 1);
        idxs[row] = idx;
    }
}

// ---------------- C2: scan counts -> offsets; new_ema_cluster_size; loss finalize ------
__global__ __launch_bounds__(256) void scan_kernel(
    const int* __restrict__ cnt, const float* __restrict__ ema_cs,
    const float* __restrict__ lossp,
    float* __restrict__ out, int* __restrict__ offs, int* __restrict__ curs) {
    __shared__ int tot[256];
    const int t = threadIdx.x;
    // loss finalize folded in (wave 0 only; independent of the scan below)
    if (t < 64) {
        float s = lossp[t];
        #pragma unroll
        for (int o = 32; o > 0; o >>= 1) s += __shfl_down(s, o);
        if (t == 0) out[O_LOSS] = s * (BETA / (float)DDIM);
    }
    const int base = t * 32;
    int local[32]; int s = 0;
    #pragma unroll
    for (int j = 0; j < 32; j++) { local[j] = cnt[base + j]; s += local[j]; }
    tot[t] = s;
    __syncthreads();
    for (int off = 1; off < 256; off <<= 1) {
        int v = (t >= off) ? tot[t - off] : 0;
        __syncthreads();
        tot[t] += v;
        __syncthreads();
    }
    int run = tot[t] - s;  // exclusive prefix
    #pragma unroll
    for (int j = 0; j < 32; j++) {
        offs[base + j] = run; curs[base + j] = run;
        out[O_CS + base + j] = DECAY * ema_cs[base + j] + ONE_MINUS_DECAY * (float)local[j];
        run += local[j];
    }
}

// ---------------- C3: fill rowlist ----------------
__global__ void fill_kernel(const int* __restrict__ idxs, int* __restrict__ curs,
                            int* __restrict__ rowlist) {
    int row = blockIdx.x * 256 + threadIdx.x;
    int idx = idxs[row];
    int pos = atomicAdd(&curs[idx], 1);
    rowlist[pos] = row;
}

// ---------------- C4: per-code EMA avg + codebook update ----------------
// 1 wave per code: gather its rows from z, fold decay + divide + active mask.
__global__ __launch_bounds__(256) void code_update_kernel(
    const float* __restrict__ z, const float* __restrict__ cb,
    const float* __restrict__ ema_cs, const float* __restrict__ ema_avg,
    const int* __restrict__ cnt, const int* __restrict__ offs,
    const int* __restrict__ rowlist, float* __restrict__ out) {
    const int lane = threadIdx.x & 63;
    const int k = blockIdx.x * 4 + (threadIdx.x >> 6);
    const int n = cnt[k], off = offs[k];
    float4 a0 = {0.f,0.f,0.f,0.f}, a1 = {0.f,0.f,0.f,0.f};
    for (int r = 0; r < n; r++) {
        int row = rowlist[off + r];
        const float4* zp = (const float4*)(z + (size_t)row * DDIM) + lane * 2;
        float4 v0 = zp[0], v1 = zp[1];
        a0.x += v0.x; a0.y += v0.y; a0.z += v0.z; a0.w += v0.w;
        a1.x += v1.x; a1.y += v1.y; a1.z += v1.z; a1.w += v1.w;
    }
    const float4* ep = (const float4*)(ema_avg + (size_t)k * DDIM) + lane * 2;
    float4 e0 = ep[0], e1 = ep[1];
    float4 n0, n1;
    n0.x = DECAY * e0.x + ONE_MINUS_DECAY * a0.x; n0.y = DECAY * e0.y + ONE_MINUS_DECAY * a0.y;
    n0.z = DECAY * e0.z + ONE_MINUS_DECAY * a0.z; n0.w = DECAY * e0.w + ONE_MINUS_DECAY * a0.w;
    n1.x = DECAY * e1.x + ONE_MINUS_DECAY * a1.x; n1.y = DECAY * e1.y + ONE_MINUS_DECAY * a1.y;
    n1.z = DECAY * e1.z + ONE_MINUS_DECAY * a1.z; n1.w = DECAY * e1.w + ONE_MINUS_DECAY * a1.w;
    ((float4*)(out + O_AVG + (size_t)k * DDIM))[lane * 2]     = n0;
    ((float4*)(out + O_AVG + (size_t)k * DDIM))[lane * 2 + 1] = n1;

    float ncs = DECAY * ema_cs[k] + ONE_MINUS_DECAY * (float)n;
    float inv = 1.0f / (ncs + EMA_EPS);
    float4 c0, c1;
    if (n > 0) {
        c0.x = n0.x * inv; c0.y = n0.y * inv; c0.z = n0.z * inv; c0.w = n0.w * inv;
        c1.x = n1.x * inv; c1.y = n1.y * inv; c1.z = n1.z * inv; c1.w = n1.w * inv;
    } else {
        const float4* cp = (const float4*)(cb + (size_t)k * DDIM) + lane * 2;
        c0 = cp[0]; c1 = cp[1];
    }
    ((float4*)(out + O_CB + (size_t)k * DDIM))[lane * 2]     = c0;
    ((float4*)(out + O_CB + (size_t)k * DDIM))[lane * 2 + 1] = c1;
}

extern "C" void kernel_launch(void* const* d_in, const int* in_sizes, int n_in,
                              void* d_out, int out_size, void* d_ws, size_t ws_size,
                              hipStream_t stream) {
    const float* z       = (const float*)d_in[0];
    const float* cb      = (const float*)d_in[1];
    const float* ema_cs  = (const float*)d_in[2];
    const float* ema_avg = (const float*)d_in[3];
    float* out = (float*)d_out;

    int* cnt       = (int*)((char*)d_ws + WS_CNT);
    float* e_sq    = (float*)((char*)d_ws + WS_ESQ);
    int* flagcnt   = (int*)((char*)d_ws + WS_FLAGCNT);
    int* flaglist  = (int*)((char*)d_ws + WS_FLAGLIST);
    unsigned long long* keys = (unsigned long long*)((char*)d_ws + WS_KEYS);
    unsigned* sec2 = (unsigned*)((char*)d_ws + WS_SEC2);
    float* lossp   = (float*)((char*)d_ws + WS_LOSSP);
    int* idxs      = (int*)((char*)d_ws + WS_IDXS);
    int* offs      = (int*)((char*)d_ws + WS_OFFS);
    int* curs      = (int*)((char*)d_ws + WS_CURS);
    int* rowlist   = (int*)((char*)d_ws + WS_ROWLIST);
    _Float16* z16  = (_Float16*)((char*)d_ws + WS_Z16);
    _Float16* cb16 = (_Float16*)((char*)d_ws + WS_CB16);

    cvtz_kernel<<<N_ROWS * DDIM / 8 / 256, 256, 0, stream>>>(z, z16, keys, sec2, lossp, flagcnt);
    cvtcb_kernel<<<KCODES, 64, 0, stream>>>(cb, cb16, e_sq, cnt);
    screen_kernel<<<dim3(N_ROWS / 128, KCODES / 128), 256, 0, stream>>>(z16, cb16, e_sq, keys, sec2);
    merge_kernel<<<N_ROWS / 256, 256, 0, stream>>>(keys, sec2, flagcnt, flaglist);
    rescore_kernel<<<dim3(KCODES / 128, RCAP / 64), 256, 0, stream>>>(z, cb, e_sq, flagcnt, flaglist, keys);
    zout_loss_kernel<<<N_ROWS / 2, 256, 0, stream>>>(z, cb, keys, out, cnt, idxs, lossp);
    scan_kernel<<<1, 256, 0, stream>>>(cnt, ema_cs, lossp, out, offs, curs);
    fill_kernel<<<N_ROWS / 256, 256, 0, stream>>>(idxs, curs, rowlist);
    code_update_kernel<<<KCODES / 4, 256, 0, stream>>>(z, cb, ema_cs, ema_avg, cnt, offs, rowlist, out);
}

// Round 7
// 618.795 us; speedup vs baseline: 1.1613x; 1.0683x over previous
//
#include <hip/hip_runtime.h>
#include <hip/hip_bf16.h>

// Problem constants
#define N_ROWS 16384   // 8*2048
#define DDIM   512
#define KCODES 8192
#define BETA   0.25f
#define DECAY  0.99f
#define ONE_MINUS_DECAY 0.01f
#define EMA_EPS 1e-5f

// Output layout (floats, concatenated in reference return order)
#define O_Z    0                 // z_out: 8388608
#define O_LOSS 8388608           // vq_loss: 1
#define O_CS   8388609           // new_ema_cluster_size: 8192
#define O_AVG  8396801           // new_ema_embed_avg: 4194304
#define O_CB   12591105          // new_codebook: 4194304

// Workspace layout (bytes), all 256-aligned; total ~25.5 MB
// (IDXS/OFFS/CURS/ROWLIST regions retained but unused since R7 tail restructure)
#define WS_CNT      0            // int[8192]            32 KB
#define WS_ESQ      32768        // float[8192]          32 KB
#define WS_FLAGCNT  65536        // int (+pad)           256 B
#define WS_FLAGLIST 65792        // int[2048]            8 KB
#define WS_KEYS     73984        // u64[16384]           128 KB
#define WS_SEC2     205056       // u32[16384]           64 KB
#define WS_LOSSP    270592       // float[64]            256 B
#define WS_IDXS     270848       // int[16384]           64 KB (unused)
#define WS_OFFS     336384       // int[8192]            32 KB (unused)
#define WS_CURS     369152       // int[8192]            32 KB (unused)
#define WS_ROWLIST  401920       // int[16384]           64 KB (unused)
#define WS_Z16      467456       // f16[16384*512]       16 MB
#define WS_CB16     17244672     // f16[8192*512]        8 MB   (end ~25.6 MB)

#define TAU  0.35f
#define RCAP 2048

typedef _Float16 half8  __attribute__((ext_vector_type(8)));
typedef float    floatx4 __attribute__((ext_vector_type(4)));

// monotone float<->u32 (ascending order preserved)
__device__ __forceinline__ unsigned enc_f(float d) {
    unsigned ub = __float_as_uint(d);
    return (ub & 0x80000000u) ? ~ub : (ub | 0x80000000u);
}
__device__ __forceinline__ float dec32(unsigned ub) {
    return __uint_as_float((ub & 0x80000000u) ? (ub ^ 0x80000000u) : ~ub);
}
__device__ __forceinline__ float dec_key(unsigned long long k) {
    return dec32((unsigned)(k >> 32));
}

__device__ __forceinline__ float4 pack8_f16(float4 a, float4 b) {
    auto p0 = __builtin_amdgcn_cvt_pkrtz(a.x, a.y);
    auto p1 = __builtin_amdgcn_cvt_pkrtz(a.z, a.w);
    auto p2 = __builtin_amdgcn_cvt_pkrtz(b.x, b.y);
    auto p3 = __builtin_amdgcn_cvt_pkrtz(b.z, b.w);
    float4 r;
    r.x = __builtin_bit_cast(float, p0);
    r.y = __builtin_bit_cast(float, p1);
    r.z = __builtin_bit_cast(float, p2);
    r.w = __builtin_bit_cast(float, p3);
    return r;
}

// global->LDS direct DMA, 16 B per lane. LDS dest = wave-uniform base + lane*16.
__device__ __forceinline__ void load_lds16(const void* g, void* l) {
    __builtin_amdgcn_global_load_lds(
        (const __attribute__((address_space(1))) unsigned int*)g,
        (__attribute__((address_space(3))) unsigned int*)l, 16, 0, 0);
}

// ---------------- prep: fused cvtz + cvtcb + inits + O_AVG prefill ----------------
// blocks [0,4096): z->f16 (8 elems/thr) + keys/sec2/lossp/flagcnt init
// blocks [4096,6144): cb->f16 + e_sq + cnt=0 (4 codes/block, 1 wave each)
// blocks [6144,8192): out[O_AVG] = DECAY * ema_avg (8 floats/thr)
__global__ __launch_bounds__(256) void prep_kernel(
    const float* __restrict__ z, const float* __restrict__ cb,
    const float* __restrict__ ema_avg,
    _Float16* __restrict__ z16, _Float16* __restrict__ cb16,
    float* __restrict__ e_sq, int* __restrict__ cnt,
    unsigned long long* __restrict__ keys, unsigned* __restrict__ sec2,
    float* __restrict__ lossp, int* __restrict__ flagcnt,
    float* __restrict__ out) {
    const int b = blockIdx.x, t = threadIdx.x;
    if (b < 4096) {
        size_t i = (size_t)b * 256 + t;   // 8 f16 elems per thread
        const float4* p = (const float4*)z + 2 * i;
        ((float4*)z16)[i] = pack8_f16(p[0], p[1]);
        if (i < N_ROWS) { keys[i] = ~0ULL; sec2[i] = 0xFFFFFFFFu; }
        if (i < 64) lossp[i] = 0.0f;
        if (i == 0) *flagcnt = 0;
    } else if (b < 6144) {
        const int k = (b - 4096) * 4 + (t >> 6);
        const int tt = t & 63;
        const float4* r = (const float4*)(cb + (size_t)k * DDIM);
        float4 a = r[2 * tt], bb = r[2 * tt + 1];
        ((float4*)(cb16 + (size_t)k * DDIM))[tt] = pack8_f16(a, bb);
        float s = a.x*a.x + a.y*a.y + a.z*a.z + a.w*a.w
                + bb.x*bb.x + bb.y*bb.y + bb.z*bb.z + bb.w*bb.w;
        #pragma unroll
        for (int o = 32; o > 0; o >>= 1) s += __shfl_down(s, o);
        if (tt == 0) { e_sq[k] = s; cnt[k] = 0; }
    } else {
        size_t i = (size_t)(b - 6144) * 256 + t;   // 2 float4 per thread
        const float4* ep = (const float4*)ema_avg + 2 * i;
        float4 e0 = ep[0], e1 = ep[1];
        float4 o0, o1;
        o0.x = DECAY * e0.x; o0.y = DECAY * e0.y; o0.z = DECAY * e0.z; o0.w = DECAY * e0.w;
        o1.x = DECAY * e1.x; o1.y = DECAY * e1.y; o1.z = DECAY * e1.z; o1.w = DECAY * e1.w;
        ((float4*)(out + O_AVG))[2 * i]     = o0;
        ((float4*)(out + O_AVG))[2 * i + 1] = o1;
    }
}

// ---------------- screen: f16 MFMA, 128x128 tile (proven 232us structure, R4-exact) ---
// 256 thr (4 waves, 2x2), wave tile 64x64, acc[4][4] -> 64 acc regs.
// LDS 32 KB; epilogue arrays aliased into zt. Best/second via atomicMin.
// NOTE: (256,4) is the register floor -- (256,5) spills acc (R3: +55% dur).
// Falsified alternatives: 8-phase (R1), 8-wave 64x32 (R5), addr-hoist (R6).
__global__ __launch_bounds__(256, 4) void screen_kernel(
    const _Float16* __restrict__ z16, const _Float16* __restrict__ cb16,
    const float* __restrict__ e_sq,
    unsigned long long* __restrict__ keys, unsigned* __restrict__ sec2) {
    __shared__ _Float16 zt[128 * 64];   // 16 KB (reused for epilogue)
    __shared__ _Float16 ct[128 * 64];   // 16 KB

    const int tid = threadIdx.x;
    const int by = blockIdx.x;   // row tile (128)
    const int bx = blockIdx.y;   // code tile (128)
    const int lane = tid & 63, wid = tid >> 6;
    const int wm = wid & 1, wn = wid >> 1;
    const int lr = lane & 15, lq = lane >> 4;

    // staging pointers: granule g = (r*4+wid)*64+lane; row=g>>3, kq=g&7;
    // source carries XOR swizzle so ds_read_b128 frags stay conflict-free.
    const _Float16* zsrc[4]; const _Float16* csrc[4];
    #pragma unroll
    for (int r = 0; r < 4; r++) {
        int g = (r * 4 + wid) * 64 + lane;
        int row = g >> 3, kq = g & 7;
        zsrc[r] = z16 + (size_t)(by * 128 + row) * DDIM + ((kq ^ (row & 7)) << 3);
        csrc[r] = cb16 + (size_t)(bx * 128 + row) * DDIM + ((kq ^ (row & 7)) << 3);
    }

    floatx4 acc[4][4];
    #pragma unroll
    for (int i = 0; i < 4; i++)
        #pragma unroll
        for (int j = 0; j < 4; j++) acc[i][j] = floatx4{0.f, 0.f, 0.f, 0.f};

    for (int kc = 0; kc < DDIM; kc += 64) {
        #pragma unroll
        for (int r = 0; r < 4; r++) load_lds16(zsrc[r] + kc, &zt[(r * 4 + wid) * 512]);
        #pragma unroll
        for (int r = 0; r < 4; r++) load_lds16(csrc[r] + kc, &ct[(r * 4 + wid) * 512]);
        __syncthreads();
        #pragma unroll
        for (int kk = 0; kk < 2; kk++) {
            half8 av[4];
            #pragma unroll
            for (int mt = 0; mt < 4; mt++) {
                int row = wm * 64 + mt * 16 + lr;
                av[mt] = *(const half8*)&zt[row * 64 + (((kk * 4 + lq) ^ (row & 7)) << 3)];
            }
            #pragma unroll
            for (int nt = 0; nt < 4; nt++) {
                int row = wn * 64 + nt * 16 + lr;
                half8 bv = *(const half8*)&ct[row * 64 + (((kk * 4 + lq) ^ (row & 7)) << 3)];
                #pragma unroll
                for (int mt = 0; mt < 4; mt++)
                    acc[mt][nt] = __builtin_amdgcn_mfma_f32_16x16x32_f16(av[mt], bv, acc[mt][nt], 0, 0, 0);
            }
        }
        __syncthreads();
    }

    // epilogue scratch aliased onto zt (all ds_reads drained by loop-end barrier)
    float* eb_d1 = (float*)zt;            // [2][128]
    int*   eb_c1 = (int*)zt + 256;        // [2][128]
    float* eb_d2 = (float*)zt + 512;      // [2][128]

    float es[4];
    #pragma unroll
    for (int nt = 0; nt < 4; nt++) es[nt] = e_sq[bx * 128 + wn * 64 + nt * 16 + lr];

    #pragma unroll
    for (int mt = 0; mt < 4; mt++) {
        #pragma unroll
        for (int r = 0; r < 4; r++) {
            float d1 = 1e30f, d2 = 1e30f; int c1 = 0x7FFFFFFF;
            #pragma unroll
            for (int nt = 0; nt < 4; nt++) {
                float d = fmaf(-2.0f, acc[mt][nt][r], es[nt]);
                int c = bx * 128 + wn * 64 + nt * 16 + lr;
                bool better = (d < d1) || (d == d1 && c < c1);
                if (better) { d2 = d1; d1 = d; c1 = c; }
                else        { d2 = fminf(d2, d); }
            }
            #pragma unroll
            for (int off = 1; off < 16; off <<= 1) {
                float od1 = __shfl_xor(d1, off);
                int   oc1 = __shfl_xor(c1, off);
                float od2 = __shfl_xor(d2, off);
                bool better = (od1 < d1) || (od1 == d1 && oc1 < c1);
                if (better) { d2 = fminf(d1, od2); d1 = od1; c1 = oc1; }
                else        { d2 = fminf(d2, od1); }
            }
            if (lr == 0) {
                int row = wm * 64 + mt * 16 + lq * 4 + r;
                eb_d1[wn * 128 + row] = d1; eb_c1[wn * 128 + row] = c1; eb_d2[wn * 128 + row] = d2;
            }
        }
    }
    __syncthreads();
    if (tid < 128) {
        float d1a = eb_d1[tid],       d2a = eb_d2[tid];       int c1a = eb_c1[tid];
        float d1b = eb_d1[128 + tid], d2b = eb_d2[128 + tid]; int c1b = eb_c1[128 + tid];
        bool bbet = (d1b < d1a) || (d1b == d1a && c1b < c1a);
        float d1 = bbet ? d1b : d1a; int c1 = bbet ? c1b : c1a;
        float d2 = bbet ? fminf(d1a, d2b) : fminf(d2a, d1b);
        unsigned long long key = ((unsigned long long)enc_f(d1) << 32) | (unsigned)c1;
        int row_g = by * 128 + tid;
        unsigned long long old = atomicMin(&keys[row_g], key);
        // second-best candidate: if we displaced old best, old's dist is a cand;
        // else our d1 is a cand. d2 always a cand. (fminf(NaN,x)=x handles init.)
        float cand = (key < old) ? fminf(dec_key(old), d2) : fminf(d1, d2);
        atomicMin(&sec2[row_g], enc_f(cand));
    }
}

// ---------------- merge: flag near-ties ----------------
__global__ void merge_kernel(unsigned long long* __restrict__ keys,
                             const unsigned* __restrict__ sec2,
                             int* __restrict__ flagcnt, int* __restrict__ flaglist) {
    int row = blockIdx.x * 256 + threadIdx.x;
    unsigned long long kb = keys[row];
    float best = dec_key(kb);
    float sec  = dec32(sec2[row]);
    if (sec - best < TAU) {
        int pos = atomicAdd(flagcnt, 1);
        if (pos < RCAP) { flaglist[pos] = row; keys[row] = ~0ULL; }
    }
}

// ---------------- rescore: exact fp32 over flagged rows ----------------
// Tile: 128 codes x 64 rows per block. k-major transposed LDS so inner-loop
// reads are ds_read_b128 (3 per k for 32 FMA) instead of 8 scalar b32 per 16.
// Per-thread 8 codes x 4 rows. fmaf chain stays k-ascending (bit-identical).
__global__ __launch_bounds__(256) void rescore_kernel(
    const float* __restrict__ z, const float* __restrict__ cb,
    const float* __restrict__ e_sq, const int* __restrict__ flagcnt,
    const int* __restrict__ flaglist, unsigned long long* __restrict__ keys) {
    int n = *flagcnt; n = min(n, RCAP);
    int base = blockIdx.y * 64;
    if (base >= n) return;
    __shared__ float ech[64][132];   // [k][code]  33.8 KB
    __shared__ float zch[64][68];    // [k][row]   17.4 KB
    __shared__ int ridx[64];
    const int tid = threadIdx.x;
    const int bx = blockIdx.x;
    if (tid < 64) ridx[tid] = flaglist[min(base + tid, n - 1)];
    __syncthreads();

    const int tc = tid & 15;   // 16 code-groups of 8
    const int tg = tid >> 4;   // 16 row-groups of 4

    // e_sq for this thread's 8 codes (registers, read once)
    float es[8];
    #pragma unroll
    for (int c = 0; c < 8; c++) es[c] = e_sq[bx * 128 + tc * 8 + c];

    float acc[4][8] = {};
    for (int kc = 0; kc < DDIM; kc += 64) {
        // stage cb -> ech transposed: 2048 float4 loads, 256 thr x 8
        #pragma unroll
        for (int l = 0; l < 8; l++) {
            int gi = tid + 256 * l;
            int code = gi >> 4, q = gi & 15;
            float4 v = *(const float4*)&cb[(size_t)(bx * 128 + code) * DDIM + kc + q * 4];
            ech[q * 4 + 0][code] = v.x; ech[q * 4 + 1][code] = v.y;
            ech[q * 4 + 2][code] = v.z; ech[q * 4 + 3][code] = v.w;
        }
        // stage z -> zch transposed: 1024 float4 loads, 256 thr x 4 (row-gather)
        #pragma unroll
        for (int l = 0; l < 4; l++) {
            int gi = tid + 256 * l;
            int row = gi >> 4, q = gi & 15;
            float4 v = *(const float4*)&z[(size_t)ridx[row] * DDIM + kc + q * 4];
            zch[q * 4 + 0][row] = v.x; zch[q * 4 + 1][row] = v.y;
            zch[q * 4 + 2][row] = v.z; zch[q * 4 + 3][row] = v.w;
        }
        __syncthreads();
        for (int k = 0; k < 64; k++) {
            const float4 b0 = *(const float4*)&ech[k][tc * 8];
            const float4 b1 = *(const float4*)&ech[k][tc * 8 + 4];
            const float4 a  = *(const float4*)&zch[k][tg * 4];
            const float ar[4] = {a.x, a.y, a.z, a.w};
            const float br[8] = {b0.x, b0.y, b0.z, b0.w, b1.x, b1.y, b1.z, b1.w};
            #pragma unroll
            for (int r = 0; r < 4; r++)
                #pragma unroll
                for (int c = 0; c < 8; c++)
                    acc[r][c] = fmaf(ar[r], br[c], acc[r][c]);
        }
        __syncthreads();
    }

    // per-thread best over its 8 codes, per row; then block reduce over 16 tc
    unsigned long long (*redk)[17] = (unsigned long long (*)[17])&ech[0][0];  // alias (64x17 u64)
    #pragma unroll
    for (int r = 0; r < 4; r++) {
        unsigned long long bk = ~0ULL;
        #pragma unroll
        for (int c = 0; c < 8; c++) {
            int code = bx * 128 + tc * 8 + c;
            float d = fmaf(-2.0f, acc[r][c], es[c]);
            unsigned long long key = ((unsigned long long)enc_f(d) << 32) | (unsigned)code;
            bk = (key < bk) ? key : bk;
        }
        redk[tg * 4 + r][tc] = bk;
    }
    __syncthreads();
    if (tid < 64) {
        unsigned long long b = redk[tid][0];
        #pragma unroll
        for (int t = 1; t < 16; t++) {
            unsigned long long v = redk[tid][t];
            b = (v < b) ? v : b;
        }
        atomicMin(&keys[ridx[tid]], b);
    }
}

// ---------------- zout: z_out, loss partials, counts, EMA scatter (2 rows/block) -------
// Replaces idxs/fill/rowlist pipeline: each thread atomically adds 0.01*z into
// out[O_AVG + idx*512 + ...] (prefilled with 0.99*ema by prep). 4 scalar atomics/thr.
__global__ __launch_bounds__(256) void zout_loss_kernel(
    const float* __restrict__ z, const float* __restrict__ cb,
    const unsigned long long* __restrict__ keys,
    float* __restrict__ out, int* __restrict__ cnt,
    float* __restrict__ lossp) {
    const int tid = threadIdx.x;
    const int sub = tid >> 7;                 // 0/1: which row of this block
    const int t   = tid & 127;
    const int row = blockIdx.x * 2 + sub;
    const int idx = (int)(unsigned int)(keys[row] & 0xFFFFFFFFull);

    const float4 zv = ((const float4*)(z  + (size_t)row * DDIM))[t];
    const float4 ev = ((const float4*)(cb + (size_t)idx * DDIM))[t];
    ((float4*)(out + O_Z + (size_t)row * DDIM))[t] = ev;

    float dx = zv.x - ev.x, dy = zv.y - ev.y, dz = zv.z - ev.z, dw = zv.w - ev.w;
    float s = dx*dx + dy*dy + dz*dz + dw*dw;

    // EMA embed-avg scatter: out[O_AVG] was prefilled with DECAY*ema_avg
    float* ap = out + O_AVG + (size_t)idx * DDIM + t * 4;
    atomicAdd(ap + 0, ONE_MINUS_DECAY * zv.x);
    atomicAdd(ap + 1, ONE_MINUS_DECAY * zv.y);
    atomicAdd(ap + 2, ONE_MINUS_DECAY * zv.z);
    atomicAdd(ap + 3, ONE_MINUS_DECAY * zv.w);

    #pragma unroll
    for (int o = 32; o > 0; o >>= 1) s += __shfl_down(s, o);
    __shared__ float red[4];
    if ((tid & 63) == 0) red[tid >> 6] = s;
    __syncthreads();
    if (t == 0) {   // tid 0 (sub 0) and tid 128 (sub 1)
        atomicAdd(&lossp[row & 63], red[sub * 2] + red[sub * 2 + 1]);
        atomicAdd(&cnt[idx], 1);
    }
}

// ---------------- finalize: new_ema_cluster_size + codebook + loss ----------------
// 4 codes/block, 1 wave each. avg already complete in out[O_AVG] (prep + zout).
__global__ __launch_bounds__(256) void finalize_kernel(
    const float* __restrict__ cb, const float* __restrict__ ema_cs,
    const int* __restrict__ cnt, const float* __restrict__ lossp,
    float* __restrict__ out) {
    const int tid = threadIdx.x;
    if (blockIdx.x == 0 && tid < 64) {   // loss finalize (wave 0 extra duty)
        float s = lossp[tid];
        #pragma unroll
        for (int o = 32; o > 0; o >>= 1) s += __shfl_down(s, o);
        if (tid == 0) out[O_LOSS] = s * (BETA / (float)DDIM);
    }
    const int lane = tid & 63;
    const int k = blockIdx.x * 4 + (tid >> 6);
    const int n = cnt[k];
    float ncs = DECAY * ema_cs[k] + ONE_MINUS_DECAY * (float)n;
    if (lane == 0) out[O_CS + k] = ncs;

    float4 c0, c1;
    if (n > 0) {
        const float inv = 1.0f / (ncs + EMA_EPS);
        const float4* ap = (const float4*)(out + O_AVG + (size_t)k * DDIM) + lane * 2;
        float4 a0 = ap[0], a1 = ap[1];
        c0.x = a0.x * inv; c0.y = a0.y * inv; c0.z = a0.z * inv; c0.w = a0.w * inv;
        c1.x = a1.x * inv; c1.y = a1.y * inv; c1.z = a1.z * inv; c1.w = a1.w * inv;
    } else {
        const float4* cp = (const float4*)(cb + (size_t)k * DDIM) + lane * 2;
        c0 = cp[0]; c1 = cp[1];
    }
    ((float4*)(out + O_CB + (size_t)k * DDIM))[lane * 2]     = c0;
    ((float4*)(out + O_CB + (size_t)k * DDIM))[lane * 2 + 1] = c1;
}

extern "C" void kernel_launch(void* const* d_in, const int* in_sizes, int n_in,
                              void* d_out, int out_size, void* d_ws, size_t ws_size,
                              hipStream_t stream) {
    const float* z       = (const float*)d_in[0];
    const float* cb      = (const float*)d_in[1];
    const float* ema_cs  = (const float*)d_in[2];
    const float* ema_avg = (const float*)d_in[3];
    float* out = (float*)d_out;

    int* cnt       = (int*)((char*)d_ws + WS_CNT);
    float* e_sq    = (float*)((char*)d_ws + WS_ESQ);
    int* flagcnt   = (int*)((char*)d_ws + WS_FLAGCNT);
    int* flaglist  = (int*)((char*)d_ws + WS_FLAGLIST);
    unsigned long long* keys = (unsigned long long*)((char*)d_ws + WS_KEYS);
    unsigned* sec2 = (unsigned*)((char*)d_ws + WS_SEC2);
    float* lossp   = (float*)((char*)d_ws + WS_LOSSP);
    _Float16* z16  = (_Float16*)((char*)d_ws + WS_Z16);
    _Float16* cb16 = (_Float16*)((char*)d_ws + WS_CB16);

    prep_kernel<<<8192, 256, 0, stream>>>(z, cb, ema_avg, z16, cb16, e_sq, cnt,
                                          keys, sec2, lossp, flagcnt, out);
    screen_kernel<<<dim3(N_ROWS / 128, KCODES / 128), 256, 0, stream>>>(z16, cb16, e_sq, keys, sec2);
    merge_kernel<<<N_ROWS / 256, 256, 0, stream>>>(keys, sec2, flagcnt, flaglist);
    rescore_kernel<<<dim3(KCODES / 128, RCAP / 64), 256, 0, stream>>>(z, cb, e_sq, flagcnt, flaglist, keys);
    zout_loss_kernel<<<N_ROWS / 2, 256, 0, stream>>>(z, cb, keys, out, cnt, lossp);
    finalize_kernel<<<KCODES / 4, 256, 0, stream>>>(cb, ema_cs, cnt, lossp, out);
}